// Round 3
// baseline (332.912 us; speedup 1.0000x reference)
//
#include <hip/hip_runtime.h>
#include <hip/hip_bf16.h>

#define NN 8192
#define DD 64

typedef __attribute__((ext_vector_type(8))) short bf16x8;
typedef __attribute__((ext_vector_type(4))) float f32x4;

// ---- K0: deg init (self-loop = 1) ----
__global__ void k0_deg_init(int* __restrict__ deg) {
  int i = blockIdx.x * 256 + threadIdx.x;
  if (i < NN) deg[i] = 1;
}

// ---- K1: in-degree histogram over dst ----
__global__ void k1_degree(const int* __restrict__ dst, int E, int* __restrict__ deg) {
  int e = blockIdx.x * 256 + threadIdx.x;
  if (e < E) atomicAdd(&deg[dst[e]], 1);
}

// ---- K2: single-block exclusive scan of (deg-1) -> rowstart; cursor init; dinv ----
__global__ void k2_scan(const int* __restrict__ deg, int* __restrict__ rowstart,
                        int* __restrict__ cursor, float* __restrict__ dinv) {
  __shared__ int part[256];
  int t = threadIdx.x;
  int base = t * 32;
  int loc[32];
  int s = 0;
#pragma unroll
  for (int i = 0; i < 32; i++) { loc[i] = s; s += deg[base + i] - 1; }
  part[t] = s;
  __syncthreads();
  for (int off = 1; off < 256; off <<= 1) {
    int u = (t >= off) ? part[t - off] : 0;
    __syncthreads();
    part[t] += u;
    __syncthreads();
  }
  int excl = (t == 0) ? 0 : part[t - 1];
#pragma unroll
  for (int i = 0; i < 32; i++) {
    int rs = excl + loc[i];
    rowstart[base + i] = rs;
    cursor[base + i] = rs;
    dinv[base + i] = rsqrtf((float)deg[base + i]);
  }
  if (t == 255) rowstart[NN] = excl + s;
}

// ---- K3: CSR fill (src lists per dst) ----
__global__ void k3_fill(const int* __restrict__ src, const int* __restrict__ dst, int E,
                        int* __restrict__ cursor, int* __restrict__ csr) {
  int e = blockIdx.x * 256 + threadIdx.x;
  if (e < E) {
    int d = dst[e];
    int pos = atomicAdd(&cursor[d], 1);
    csr[pos] = src[e];
  }
}

// ---- K4: h = x @ W  (W in LDS, 4 rows per block, 1 wave per row) ----
__global__ void k4_xw(const float* __restrict__ x, const float* __restrict__ W,
                      float* __restrict__ h) {
  __shared__ float Wl[64 * 64];
  __shared__ float xl[4 * 64];
  int t = threadIdx.x;
#pragma unroll
  for (int i = 0; i < 16; i++) Wl[t + 256 * i] = W[t + 256 * i];
  int row0 = blockIdx.x * 4;
  xl[t] = x[row0 * 64 + t];
  __syncthreads();
  int r = t >> 6, d = t & 63;
  float acc = 0.f;
#pragma unroll
  for (int k = 0; k < 64; k++) acc += xl[r * 64 + k] * Wl[k * 64 + d];
  h[(row0 + r) * 64 + d] = acc;
}

// ---- K5: per-node gather-aggregate + self-loop + bias + relu -> bf16 H ----
__global__ void k5_agg(const float* __restrict__ h, const int* __restrict__ rowstart,
                       const int* __restrict__ csr, const float* __restrict__ dinv,
                       const float* __restrict__ b, unsigned short* __restrict__ hb) {
  int i = (blockIdx.x * 256 + threadIdx.x) >> 6;  // node = global wave id
  int lane = threadIdx.x & 63;
  float di = dinv[i];
  float acc = di * di * h[i * 64 + lane];  // self-loop
  int s0 = rowstart[i], s1 = rowstart[i + 1];
  for (int j = s0; j < s1; j++) {
    int s = csr[j];
    acc += di * dinv[s] * h[s * 64 + lane];
  }
  acc += b[lane];
  acc = fmaxf(acc, 0.f);
  __hip_bfloat16 bv = __float2bfloat16(acc);
  hb[i * 64 + lane] = *reinterpret_cast<unsigned short*>(&bv);
}

// ---- K6: C = H @ H^T, bf16 MFMA 16x16x32, 128x128 tile, 4 waves x (64x64) ----
__global__ __launch_bounds__(256) void k6_gemm(const unsigned short* __restrict__ Hb,
                                               float* __restrict__ C) {
  int t = threadIdx.x;
  int w = t >> 6, lane = t & 63;
  int wm = w >> 1, wn = w & 1;
  int m0 = blockIdx.y * 128 + wm * 64;
  int n0 = blockIdx.x * 128 + wn * 64;
  int r = lane & 15, g = lane >> 4;

  bf16x8 a[4][2], bf[4][2];
#pragma unroll
  for (int mi = 0; mi < 4; mi++) {
#pragma unroll
    for (int s = 0; s < 2; s++) {
      a[mi][s] = *reinterpret_cast<const bf16x8*>(&Hb[(m0 + 16 * mi + r) * 64 + 32 * s + 8 * g]);
      bf[mi][s] = *reinterpret_cast<const bf16x8*>(&Hb[(n0 + 16 * mi + r) * 64 + 32 * s + 8 * g]);
    }
  }

  f32x4 acc[4][4];
#pragma unroll
  for (int mi = 0; mi < 4; mi++)
#pragma unroll
    for (int ni = 0; ni < 4; ni++) acc[mi][ni] = (f32x4){0.f, 0.f, 0.f, 0.f};

#pragma unroll
  for (int s = 0; s < 2; s++)
#pragma unroll
    for (int mi = 0; mi < 4; mi++)
#pragma unroll
      for (int ni = 0; ni < 4; ni++)
        acc[mi][ni] = __builtin_amdgcn_mfma_f32_16x16x32_bf16(a[mi][s], bf[ni][s],
                                                              acc[mi][ni], 0, 0, 0);

#pragma unroll
  for (int mi = 0; mi < 4; mi++) {
#pragma unroll
    for (int rr = 0; rr < 4; rr++) {
      int row = m0 + 16 * mi + 4 * g + rr;
#pragma unroll
      for (int ni = 0; ni < 4; ni++) {
        C[row * NN + n0 + 16 * ni + r] = acc[mi][ni][rr];
      }
    }
  }
}

extern "C" void kernel_launch(void* const* d_in, const int* in_sizes, int n_in,
                              void* d_out, int out_size, void* d_ws, size_t ws_size,
                              hipStream_t stream) {
  const float* x = (const float*)d_in[0];
  const int* ei = (const int*)d_in[1];
  const float* W = (const float*)d_in[2];
  const float* b = (const float*)d_in[3];
  float* C = (float*)d_out;
  int E = in_sizes[1] / 2;
  const int* src = ei;
  const int* dst = ei + E;

  // Workspace layout (256B-aligned regions).
  // BUGFIX R1: rowstart needs NN+1 ints (32772 B); previously its last write
  // clobbered cursor[0] -> csr overflow -> poisoned csr -> wild read -> abort.
  char* ws = (char*)d_ws;
  int* deg       = (int*)(ws + 0);        // 8192 ints  -> [0,      32768)
  int* rowstart  = (int*)(ws + 32768);    // 8193 ints  -> [32768,  65540) pad to 65792
  int* cursor    = (int*)(ws + 65792);    // 8192 ints  -> [65792,  98560)
  float* dinv    = (float*)(ws + 98560);  // 8192 f32   -> [98560,  131328)
  int* csr       = (int*)(ws + 131328);   // E ints     -> [131328, 1179904)
  float* h       = (float*)(ws + 1179904);            // 2 MB -> [1179904, 3277056)
  unsigned short* hb = (unsigned short*)(ws + 3277056); // 1 MB -> [3277056, 4325632)

  int eb = (E + 255) / 256;
  k0_deg_init<<<32, 256, 0, stream>>>(deg);
  k1_degree<<<eb, 256, 0, stream>>>(dst, E, deg);
  k2_scan<<<1, 256, 0, stream>>>(deg, rowstart, cursor, dinv);
  k3_fill<<<eb, 256, 0, stream>>>(src, dst, E, cursor, csr);
  k4_xw<<<NN / 4, 256, 0, stream>>>(x, W, h);
  k5_agg<<<NN / 4, 256, 0, stream>>>(h, rowstart, csr, dinv, b, hb);
  dim3 g(NN / 128, NN / 128);
  k6_gemm<<<g, 256, 0, stream>>>(hb, C);
}